// Round 4
// baseline (696.196 us; speedup 1.0000x reference)
//
#include <hip/hip_runtime.h>
#include <hip/hip_bf16.h>
#include <math.h>

#define N_CELLS 512
#define N_GENES 256
#define D 128
#define HEADS 4
#define HD 32
#define E_SP 8192
#define E_GRN 2048

typedef __attribute__((ext_vector_type(8))) short bf16x8;
typedef __attribute__((ext_vector_type(4))) float f32x4;

// ---------------- utility ----------------

__device__ __forceinline__ float gelu_exact(float x) {
    return 0.5f * x * (1.0f + erff(x * 0.70710678118654752f));
}

__device__ __forceinline__ unsigned short f2bf(float f) {
    unsigned u = __float_as_uint(f);
    return (unsigned short)((u + 0x7FFFu + ((u >> 16) & 1u)) >> 16);
}

__device__ __forceinline__ float blo(unsigned u) { return __uint_as_float(u << 16); }
__device__ __forceinline__ float bhi(unsigned u) { return __uint_as_float(u & 0xFFFF0000u); }
__device__ __forceinline__ float bdot(unsigned a, unsigned b) {
    return blo(a) * blo(b) + bhi(a) * bhi(b);
}

template<int NT>
__device__ __forceinline__ float blockSum(float v, float* sbuf) {
    #pragma unroll
    for (int off = 32; off > 0; off >>= 1) v += __shfl_down(v, off, 64);
    int lane = threadIdx.x & 63, wid = threadIdx.x >> 6;
    __syncthreads();
    if (lane == 0) sbuf[wid] = v;
    __syncthreads();
    float r = 0.f;
    #pragma unroll
    for (int i = 0; i < NT / 64; ++i) r += sbuf[i];
    return r;
}

// ---------------- spatial CSR build (512 bins) ----------------

__global__ __launch_bounds__(512) void sp_csr_kernel(const int* __restrict__ sp,
                                                     int* __restrict__ sp_off,
                                                     int* __restrict__ sp_src) {
    __shared__ int cnt[512];
    __shared__ int scan[512];
    __shared__ int cur[512];
    int t = threadIdx.x;
    cnt[t] = 0;
    __syncthreads();
    for (int e = t; e < E_SP; e += 512) atomicAdd(&cnt[sp[E_SP + e]], 1);
    __syncthreads();
    scan[t] = cnt[t];
    __syncthreads();
    #pragma unroll
    for (int s = 1; s < 512; s <<= 1) {
        int v = (t >= s) ? scan[t - s] : 0;
        __syncthreads();
        scan[t] += v;
        __syncthreads();
    }
    int excl = scan[t] - cnt[t];
    sp_off[t] = excl;
    if (t == 511) sp_off[512] = scan[511];
    cur[t] = excl;
    __syncthreads();
    for (int e = t; e < E_SP; e += 512) {
        int dst = sp[E_SP + e];
        int pos = atomicAdd(&cur[dst], 1);
        sp_src[pos] = sp[e];
    }
}

// ---------------- gene CSR build (256 bins) ----------------

__global__ __launch_bounds__(256) void gene_csr_kernel(const int* __restrict__ grn,
                                                       int* __restrict__ csr_off,
                                                       int* __restrict__ csr_src) {
    __shared__ int cnt[N_GENES];
    __shared__ int scan[N_GENES];
    __shared__ int cur[N_GENES];
    int t = threadIdx.x;
    cnt[t] = 0;
    __syncthreads();
    for (int e = t; e < E_GRN; e += 256) atomicAdd(&cnt[grn[E_GRN + e]], 1);
    __syncthreads();
    scan[t] = cnt[t];
    __syncthreads();
    #pragma unroll
    for (int s = 1; s < 256; s <<= 1) {
        int v = (t >= s) ? scan[t - s] : 0;
        __syncthreads();
        scan[t] += v;
        __syncthreads();
    }
    int excl = scan[t] - cnt[t];
    csr_off[t] = excl;
    if (t == 255) csr_off[256] = scan[255];
    cur[t] = excl;
    __syncthreads();
    for (int e = t; e < E_GRN; e += 256) {
        int dst = grn[E_GRN + e];
        int pos = atomicAdd(&cur[dst], 1);
        csr_src[pos] = grn[e];
    }
}

// ---------------- GIN MLP with inline CSR gather ----------------

__global__ __launch_bounds__(256) void gin_mlp_kernel(
    const float* __restrict__ high,
    const int* __restrict__ sp_off, const int* __restrict__ sp_src,
    const float* __restrict__ eps,
    const float* __restrict__ w1, const float* __restrict__ b1,
    const float* __restrict__ w2, const float* __restrict__ b2,
    const float* __restrict__ lng, const float* __restrict__ lnb,
    float* __restrict__ high_out) {
    int c = blockIdx.x;
    int t = threadIdx.x;
    __shared__ float h[D];
    __shared__ float h1[2 * D];
    __shared__ float sbuf[4];
    if (t < D) {
        float acc = 0.f;
        int off = sp_off[c], end = sp_off[c + 1];
        for (int i = off; i < end; ++i) acc += high[(size_t)sp_src[i] * D + t];
        h[t] = (1.f + eps[0]) * high[c * D + t] + acc;
    }
    __syncthreads();
    float a = b1[t];
    for (int k = 0; k < D; ++k) a += h[k] * w1[k * 256 + t];
    h1[t] = gelu_exact(a);
    __syncthreads();
    float x = 0.f;
    if (t < D) {
        float a2 = b2[t];
        for (int k = 0; k < 256; ++k) a2 += h1[k] * w2[k * D + t];
        x = a2;
    }
    float s = blockSum<256>(x, sbuf);
    float mean = s * (1.f / 128.f);
    float xm = (t < D) ? (x - mean) : 0.f;
    float var = blockSum<256>(xm * xm, sbuf) * (1.f / 128.f);
    if (t < D) high_out[c * D + t] = xm * rsqrtf(var + 1e-5f) * lng[t] + lnb[t];
}

// ---------------- weight transpose + bf16 cast: Wt[w][n][k] ----------------

__global__ __launch_bounds__(256) void wt_kernel(
    const float* __restrict__ wq, const float* __restrict__ wk,
    const float* __restrict__ wv, const float* __restrict__ wskip,
    unsigned short* __restrict__ wt4) {
    __shared__ float tile[128][132];
    int w = blockIdx.x;
    const float* Wp = (w == 0) ? wq : (w == 1) ? wk : (w == 2) ? wv : wskip;
    int t = threadIdx.x;
    #pragma unroll
    for (int rep = 0; rep < 16; ++rep) {
        int f4 = rep * 256 + t;
        float4 v = ((const float4*)Wp)[f4];
        int f = f4 * 4;
        int k = f >> 7, n = f & 127;
        tile[k][n] = v.x; tile[k][n + 1] = v.y; tile[k][n + 2] = v.z; tile[k][n + 3] = v.w;
    }
    __syncthreads();
    unsigned short* out = wt4 + (size_t)w * 16384;
    #pragma unroll
    for (int rep = 0; rep < 16; ++rep) {
        int f4 = rep * 256 + t;
        int f = f4 * 4;
        int n = f >> 7, k = f & 127;
        ushort4 o;
        o.x = f2bf(tile[k][n]);
        o.y = f2bf(tile[k + 1][n]);
        o.z = f2bf(tile[k + 2][n]);
        o.w = f2bf(tile[k + 3][n]);
        *(ushort4*)(out + (size_t)n * 128 + k) = o;
    }
}

// ---------------- fused 4-weight MFMA projection ----------------

__global__ __launch_bounds__(256, 2) void proj4_kernel(
    const float* __restrict__ X,
    const unsigned short* __restrict__ Wt4,
    const float* __restrict__ bq, const float* __restrict__ bk,
    const float* __restrict__ bv, const float* __restrict__ bs,
    unsigned short* __restrict__ Yq, unsigned short* __restrict__ Yk,
    unsigned short* __restrict__ Yv, float* __restrict__ Yskip) {
    __shared__ short Xs[128 * 128];
    __shared__ short Ws[128 * 128];
    int t = threadIdx.x;
    int lane = t & 63, wid = t >> 6;
    const float* Xblk = X + (size_t)blockIdx.x * 128 * 128;

    #pragma unroll
    for (int rep = 0; rep < 16; ++rep) {
        int f4 = rep * 256 + t;
        float4 xv = ((const float4*)Xblk)[f4];
        int f = f4 * 4;
        int row = f >> 7, k = f & 127;
        unsigned p0 = (unsigned)f2bf(xv.x) | ((unsigned)f2bf(xv.y) << 16);
        unsigned p1 = (unsigned)f2bf(xv.z) | ((unsigned)f2bf(xv.w) << 16);
        int eidx = (row * 128 + k) ^ ((row & 7) << 3);
        *(uint2*)(&Xs[eidx]) = make_uint2(p0, p1);
    }

    const float* Bs_[4] = {bq, bk, bv, bs};
    int lr = lane & 15, lg = lane >> 4;
    int rbase = (wid >> 1) * 64, cbase = (wid & 1) * 64;
    int orow0 = blockIdx.x * 128 + rbase;

    for (int w = 0; w < 4; ++w) {
        __syncthreads();
        const uint2* Wsrc = (const uint2*)(Wt4 + (size_t)w * 16384);
        #pragma unroll
        for (int rep = 0; rep < 16; ++rep) {
            int e4 = rep * 256 + t;
            uint2 d2 = Wsrc[e4];
            int f = e4 * 4;
            int n = f >> 7, k = f & 127;
            *(uint2*)(&Ws[(n * 128 + k) ^ ((n & 7) << 3)]) = d2;
        }
        __syncthreads();

        f32x4 acc[4][4] = {};
        #pragma unroll
        for (int ks = 0; ks < 4; ++ks) {
            int k0 = ks * 32 + lg * 8;
            bf16x8 a[4], b[4];
            #pragma unroll
            for (int m = 0; m < 4; ++m) {
                int row = rbase + m * 16 + lr;
                a[m] = *(const bf16x8*)(&Xs[(row * 128 + k0) ^ ((row & 7) << 3)]);
            }
            #pragma unroll
            for (int n = 0; n < 4; ++n) {
                int col = cbase + n * 16 + lr;
                b[n] = *(const bf16x8*)(&Ws[(col * 128 + k0) ^ ((col & 7) << 3)]);
            }
            #pragma unroll
            for (int m = 0; m < 4; ++m)
                #pragma unroll
                for (int n = 0; n < 4; ++n)
                    acc[m][n] = __builtin_amdgcn_mfma_f32_16x16x32_bf16(a[m], b[n], acc[m][n], 0, 0, 0);
        }

        const float* Bb = Bs_[w];
        if (w < 3) {
            unsigned short* Y = (w == 0) ? Yq : (w == 1) ? Yk : Yv;
            #pragma unroll
            for (int n = 0; n < 4; ++n) {
                int col = cbase + n * 16 + lr;
                float bias = Bb[col];
                #pragma unroll
                for (int m = 0; m < 4; ++m)
                    #pragma unroll
                    for (int j = 0; j < 4; ++j) {
                        int row = orow0 + m * 16 + lg * 4 + j;
                        Y[(size_t)row * 128 + col] = f2bf(acc[m][n][j] + bias);
                    }
            }
        } else {
            #pragma unroll
            for (int n = 0; n < 4; ++n) {
                int col = cbase + n * 16 + lr;
                float bias = Bb[col];
                #pragma unroll
                for (int m = 0; m < 4; ++m)
                    #pragma unroll
                    for (int j = 0; j < 4; ++j) {
                        int row = orow0 + m * 16 + lg * 4 + j;
                        Yskip[(size_t)row * 128 + col] = acc[m][n][j] + bias;
                    }
            }
        }
    }
}

// ---------------- fused edge attention: logits + softmax + PV + skip + LN ----------------
// One block per cell, 8 waves, dynamic LDS: kv 64KB (K then V) + alpha 32KB

__global__ __launch_bounds__(512) void attn_fused_kernel(
    const unsigned short* __restrict__ q, const unsigned short* __restrict__ k,
    const unsigned short* __restrict__ v,
    const int* __restrict__ csr_off, const int* __restrict__ csr_src,
    const float* __restrict__ lng, const float* __restrict__ lnb,
    float* __restrict__ out) {
    extern __shared__ char smem[];
    unsigned short* kv = (unsigned short*)smem;          // 32768 bf16 = 64KB
    float* alpha = (float*)(smem + 65536);               // 8192 f32 = 32KB
    int c = blockIdx.x;
    int t = threadIdx.x, lane = t & 63, wid = t >> 6;
    int h = lane >> 4, r = lane & 15;
    const size_t cbase = (size_t)c * N_GENES * D;        // 32768 elems

    // ---- stage K ----
    {
        const uint4* s4 = (const uint4*)(k + cbase);
        uint4* d4 = (uint4*)kv;
        #pragma unroll
        for (int i = 0; i < 8; ++i) d4[i * 512 + t] = s4[i * 512 + t];
    }
    __syncthreads();

    // ---- phase 1: logits (CSR order) + segment softmax, wave-local ----
    uint qv_next = *(const uint*)(q + cbase + (size_t)wid * D + 2 * lane);
    for (int it = 0; it < 32; ++it) {
        int g = it * 8 + wid;
        uint qv = qv_next;
        if (it < 31)
            qv_next = *(const uint*)(q + cbase + (size_t)(g + 8) * D + 2 * lane);
        int off = csr_off[g], end = csr_off[g + 1];
        for (int i = off; i < end; ++i) {
            int sg = csr_src[i];
            uint kk = *(const uint*)(kv + sg * D + 2 * lane);
            float p = bdot(qv, kk);
            p += __shfl_xor(p, 1);
            p += __shfl_xor(p, 2);
            p += __shfl_xor(p, 4);
            p += __shfl_xor(p, 8);
            if (r == 0) alpha[i * 4 + h] = p * 0.17677669529663687f;
        }
        // softmax over segment (per head, 16 lanes strided)
        float m = -1e30f;
        for (int i = off + r; i < end; i += 16) m = fmaxf(m, alpha[i * 4 + h]);
        m = fmaxf(m, __shfl_xor(m, 1));
        m = fmaxf(m, __shfl_xor(m, 2));
        m = fmaxf(m, __shfl_xor(m, 4));
        m = fmaxf(m, __shfl_xor(m, 8));
        float s = 0.f;
        for (int i = off + r; i < end; i += 16) {
            float e = expf(alpha[i * 4 + h] - m);
            alpha[i * 4 + h] = e;
            s += e;
        }
        s += __shfl_xor(s, 1);
        s += __shfl_xor(s, 2);
        s += __shfl_xor(s, 4);
        s += __shfl_xor(s, 8);
        float inv = 1.f / s;
        for (int i = off + r; i < end; i += 16) alpha[i * 4 + h] *= inv;
    }
    __syncthreads();

    // ---- stage V (reuse kv buffer) ----
    {
        const uint4* s4 = (const uint4*)(v + cbase);
        uint4* d4 = (uint4*)kv;
        #pragma unroll
        for (int i = 0; i < 8; ++i) d4[i * 512 + t] = s4[i * 512 + t];
    }
    __syncthreads();

    // ---- phase 2: PV + skip + LayerNorm ----
    float2 lg = *(const float2*)(lng + 2 * lane);
    float2 lb = *(const float2*)(lnb + 2 * lane);
    float2 sk_next = *(const float2*)(out + cbase + (size_t)wid * D + 2 * lane);
    for (int it = 0; it < 32; ++it) {
        int g = it * 8 + wid;
        float ax = sk_next.x, ay = sk_next.y;
        if (it < 31)
            sk_next = *(const float2*)(out + cbase + (size_t)(g + 8) * D + 2 * lane);
        int off = csr_off[g], end = csr_off[g + 1];
        for (int i = off; i < end; ++i) {
            float a = alpha[i * 4 + h];
            int sg = csr_src[i];
            uint vv = *(const uint*)(kv + sg * D + 2 * lane);
            ax += a * blo(vv);
            ay += a * bhi(vv);
        }
        float s = ax + ay;
        s += __shfl_xor(s, 1);  s += __shfl_xor(s, 2);  s += __shfl_xor(s, 4);
        s += __shfl_xor(s, 8);  s += __shfl_xor(s, 16); s += __shfl_xor(s, 32);
        float mean = s * (1.f / 128.f);
        float dx = ax - mean, dy = ay - mean;
        float vs = dx * dx + dy * dy;
        vs += __shfl_xor(vs, 1);  vs += __shfl_xor(vs, 2);  vs += __shfl_xor(vs, 4);
        vs += __shfl_xor(vs, 8);  vs += __shfl_xor(vs, 16); vs += __shfl_xor(vs, 32);
        float var = vs * (1.f / 128.f);
        float rs = rsqrtf(var + 1e-5f);
        float2 o;
        o.x = dx * rs * lg.x + lb.x;
        o.y = dy * rs * lg.y + lb.y;
        *(float2*)(out + cbase + (size_t)g * D + 2 * lane) = o;
    }
}

// ---------------- gene aggregation ----------------

__global__ __launch_bounds__(128) void gene_agg_kernel(
    const float* __restrict__ low_out,
    const float* __restrict__ agg_w, const float* __restrict__ agg_b,
    float* __restrict__ gene_agg) {
    int c = blockIdx.x, d = threadIdx.x;
    const float* base = low_out + (size_t)c * N_GENES * D;
    float s = 0.f;
    for (int g = 0; g < N_GENES; ++g) s += base[g * D + d];
    __shared__ float m[D];
    m[d] = s * (1.f / 256.f);
    __syncthreads();
    float acc = agg_b[d];
    for (int k = 0; k < D; ++k) acc += m[k] * agg_w[k * D + d];
    gene_agg[c * D + d] = gelu_exact(acc);
}

// ---------------- cross gating + high LayerNorm ----------------

__global__ __launch_bounds__(128) void cross_kernel(
    const float* __restrict__ high_emb, const float* __restrict__ high_out,
    const float* __restrict__ gene_agg,
    const float* __restrict__ cw, const float* __restrict__ cb,
    const float* __restrict__ nhg, const float* __restrict__ nhb,
    float* __restrict__ high_new, float* __restrict__ low_cross) {
    int c = blockIdx.x, d = threadIdx.x;
    __shared__ float ho[D], ga[D];
    __shared__ float sbuf[2];
    ho[d] = high_out[c * D + d];
    ga[d] = gene_agg[c * D + d];
    __syncthreads();
    float q1 = cb[0 * D + d], k1 = cb[1 * D + d], v1 = cb[2 * D + d];
    float q2 = cb[3 * D + d], k2 = cb[4 * D + d], v2 = cb[5 * D + d];
    for (int k = 0; k < D; ++k) {
        float hv = ho[k], gv = ga[k];
        q1 += hv * cw[0 * 16384 + k * D + d];
        k1 += gv * cw[1 * 16384 + k * D + d];
        v1 += gv * cw[2 * 16384 + k * D + d];
        q2 += gv * cw[3 * 16384 + k * D + d];
        k2 += hv * cw[4 * 16384 + k * D + d];
        v2 += hv * cw[5 * 16384 + k * D + d];
    }
    const float scale = 0.08838834764831845f;
    float s1 = blockSum<128>(q1 * k1, sbuf);
    float s2 = blockSum<128>(q2 * k2, sbuf);
    float hc = (1.f / (1.f + expf(-s1 * scale))) * v1;
    float lc = (1.f / (1.f + expf(-s2 * scale))) * v2;
    low_cross[c * D + d] = lc;
    float x = high_emb[c * D + d] + ho[d] + hc;
    float sm = blockSum<128>(x, sbuf);
    float mean = sm * (1.f / 128.f);
    float xm = x - mean;
    float var = blockSum<128>(xm * xm, sbuf) * (1.f / 128.f);
    high_new[c * D + d] = xm * rsqrtf(var + 1e-5f) * nhg[d] + nhb[d];
}

// ---------------- final low LayerNorm ----------------

__global__ __launch_bounds__(128) void low_final_kernel(
    const float* __restrict__ low_emb, const float* __restrict__ low_cross,
    const float* __restrict__ nlg, const float* __restrict__ nlb,
    float* __restrict__ out) {
    int cg = blockIdx.x;
    int c = cg >> 8;
    int d = threadIdx.x;
    size_t idx = (size_t)cg * D + d;
    float x = low_emb[idx] + out[idx] + low_cross[c * D + d];
    __shared__ float sbuf[2];
    float s = blockSum<128>(x, sbuf);
    float mean = s * (1.f / 128.f);
    float xm = x - mean;
    float var = blockSum<128>(xm * xm, sbuf) * (1.f / 128.f);
    out[idx] = xm * rsqrtf(var + 1e-5f) * nlg[d] + nlb[d];
}

// ---------------- launch ----------------

extern "C" void kernel_launch(void* const* d_in, const int* in_sizes, int n_in,
                              void* d_out, int out_size, void* d_ws, size_t ws_size,
                              hipStream_t stream) {
    const float* high_emb = (const float*)d_in[0];
    const float* low_emb  = (const float*)d_in[1];
    const int*   sp       = (const int*)d_in[2];
    const int*   grn      = (const int*)d_in[3];
    const float* gin_w1   = (const float*)d_in[4];
    const float* gin_b1   = (const float*)d_in[5];
    const float* gin_w2   = (const float*)d_in[6];
    const float* gin_b2   = (const float*)d_in[7];
    const float* gin_eps  = (const float*)d_in[8];
    const float* gin_lng  = (const float*)d_in[9];
    const float* gin_lnb  = (const float*)d_in[10];
    const float* tc_wq    = (const float*)d_in[11];
    const float* tc_bq    = (const float*)d_in[12];
    const float* tc_wk    = (const float*)d_in[13];
    const float* tc_bk    = (const float*)d_in[14];
    const float* tc_wv    = (const float*)d_in[15];
    const float* tc_bv    = (const float*)d_in[16];
    const float* tc_wskip = (const float*)d_in[17];
    const float* tc_bskip = (const float*)d_in[18];
    const float* tc_lng   = (const float*)d_in[19];
    const float* tc_lnb   = (const float*)d_in[20];
    const float* cross_w  = (const float*)d_in[21];
    const float* cross_b  = (const float*)d_in[22];
    const float* agg_w    = (const float*)d_in[23];
    const float* agg_b    = (const float*)d_in[24];
    const float* nh_g     = (const float*)d_in[25];
    const float* nh_b     = (const float*)d_in[26];
    const float* nl_g     = (const float*)d_in[27];
    const float* nl_b     = (const float*)d_in[28];

    float* out = (float*)d_out;
    float* out_high = out;
    float* out_low  = out + N_CELLS * D;

    const size_t LOW_N = (size_t)N_CELLS * N_GENES * D;   // 16777216

    unsigned short* q_b = (unsigned short*)d_ws;
    unsigned short* k_b = q_b + LOW_N;
    unsigned short* v_b = k_b + LOW_N;
    float* ws_high_out  = (float*)(v_b + LOW_N);
    float* ws_gene_agg  = ws_high_out + N_CELLS * D;
    float* ws_low_cross = ws_gene_agg + N_CELLS * D;
    unsigned short* wt4 = (unsigned short*)(ws_low_cross + N_CELLS * D);
    int* csr_off = (int*)(wt4 + 4 * 128 * 128);
    int* csr_src = csr_off + 260;
    int* sp_off  = csr_src + E_GRN;
    int* sp_src  = sp_off + 516;

    // CSR builds + weight transpose (independent)
    sp_csr_kernel<<<1, 512, 0, stream>>>(sp, sp_off, sp_src);
    gene_csr_kernel<<<1, 256, 0, stream>>>(grn, csr_off, csr_src);
    wt_kernel<<<4, 256, 0, stream>>>(tc_wq, tc_wk, tc_wv, tc_wskip, wt4);

    // high level GIN (gather fused)
    gin_mlp_kernel<<<N_CELLS, 256, 0, stream>>>(high_emb, sp_off, sp_src, gin_eps,
        gin_w1, gin_b1, gin_w2, gin_b2, gin_lng, gin_lnb, ws_high_out);

    // fused 4-weight projection (MFMA)
    proj4_kernel<<<N_CELLS * N_GENES / 128, 256, 0, stream>>>(
        low_emb, wt4, tc_bq, tc_bk, tc_bv, tc_bskip, q_b, k_b, v_b, out_low);

    // fused attention: logits + softmax + PV + skip + LN
    attn_fused_kernel<<<N_CELLS, 512, 98304, stream>>>(
        q_b, k_b, v_b, csr_off, csr_src, tc_lng, tc_lnb, out_low);

    // gene aggregation
    gene_agg_kernel<<<N_CELLS, 128, 0, stream>>>(out_low, agg_w, agg_b, ws_gene_agg);

    // cross gating + high LN
    cross_kernel<<<N_CELLS, 128, 0, stream>>>(high_emb, ws_high_out, ws_gene_agg,
        cross_w, cross_b, nh_g, nh_b, out_high, ws_low_cross);

    // final low LN
    low_final_kernel<<<N_CELLS * N_GENES, 128, 0, stream>>>(
        low_emb, ws_low_cross, nl_g, nl_b, out_low);
}

// Round 5
// 616.449 us; speedup vs baseline: 1.1294x; 1.1294x over previous
//
#include <hip/hip_runtime.h>
#include <hip/hip_bf16.h>
#include <math.h>

#define N_CELLS 512
#define N_GENES 256
#define D 128
#define HEADS 4
#define HD 32
#define E_SP 8192
#define E_GRN 2048

typedef __attribute__((ext_vector_type(8))) short bf16x8;
typedef __attribute__((ext_vector_type(4))) float f32x4;

// ---------------- utility ----------------

__device__ __forceinline__ float gelu_exact(float x) {
    return 0.5f * x * (1.0f + erff(x * 0.70710678118654752f));
}

__device__ __forceinline__ unsigned short f2bf(float f) {
    unsigned u = __float_as_uint(f);
    return (unsigned short)((u + 0x7FFFu + ((u >> 16) & 1u)) >> 16);
}

template<int NT>
__device__ __forceinline__ float blockSum(float v, float* sbuf) {
    #pragma unroll
    for (int off = 32; off > 0; off >>= 1) v += __shfl_down(v, off, 64);
    int lane = threadIdx.x & 63, wid = threadIdx.x >> 6;
    __syncthreads();
    if (lane == 0) sbuf[wid] = v;
    __syncthreads();
    float r = 0.f;
    #pragma unroll
    for (int i = 0; i < NT / 64; ++i) r += sbuf[i];
    return r;
}

// ---------------- spatial CSR build (512 bins) ----------------

__global__ __launch_bounds__(512) void sp_csr_kernel(const int* __restrict__ sp,
                                                     int* __restrict__ sp_off,
                                                     int* __restrict__ sp_src) {
    __shared__ int cnt[512];
    __shared__ int scan[512];
    __shared__ int cur[512];
    int t = threadIdx.x;
    cnt[t] = 0;
    __syncthreads();
    for (int e = t; e < E_SP; e += 512) atomicAdd(&cnt[sp[E_SP + e]], 1);
    __syncthreads();
    scan[t] = cnt[t];
    __syncthreads();
    #pragma unroll
    for (int s = 1; s < 512; s <<= 1) {
        int v = (t >= s) ? scan[t - s] : 0;
        __syncthreads();
        scan[t] += v;
        __syncthreads();
    }
    int excl = scan[t] - cnt[t];
    sp_off[t] = excl;
    if (t == 511) sp_off[512] = scan[511];
    cur[t] = excl;
    __syncthreads();
    for (int e = t; e < E_SP; e += 512) {
        int dst = sp[E_SP + e];
        int pos = atomicAdd(&cur[dst], 1);
        sp_src[pos] = sp[e];
    }
}

// ---------------- GRN multiplicity counts, 4-bit packed: cnt4[dst*32 + src/8] ----------------

__global__ void cnt_build_kernel(const int* __restrict__ grn, unsigned* __restrict__ cnt4) {
    int e = blockIdx.x * 256 + threadIdx.x;
    int src = grn[e], dst = grn[E_GRN + e];
    atomicAdd(&cnt4[dst * 32 + (src >> 3)], 1u << (4 * (src & 7)));
}

// ---------------- GIN MLP with inline CSR gather ----------------

__global__ __launch_bounds__(256) void gin_mlp_kernel(
    const float* __restrict__ high,
    const int* __restrict__ sp_off, const int* __restrict__ sp_src,
    const float* __restrict__ eps,
    const float* __restrict__ w1, const float* __restrict__ b1,
    const float* __restrict__ w2, const float* __restrict__ b2,
    const float* __restrict__ lng, const float* __restrict__ lnb,
    float* __restrict__ high_out) {
    int c = blockIdx.x;
    int t = threadIdx.x;
    __shared__ float h[D];
    __shared__ float h1[2 * D];
    __shared__ float sbuf[4];
    if (t < D) {
        float acc = 0.f;
        int off = sp_off[c], end = sp_off[c + 1];
        for (int i = off; i < end; ++i) acc += high[(size_t)sp_src[i] * D + t];
        h[t] = (1.f + eps[0]) * high[c * D + t] + acc;
    }
    __syncthreads();
    float a = b1[t];
    for (int k = 0; k < D; ++k) a += h[k] * w1[k * 256 + t];
    h1[t] = gelu_exact(a);
    __syncthreads();
    float x = 0.f;
    if (t < D) {
        float a2 = b2[t];
        for (int k = 0; k < 256; ++k) a2 += h1[k] * w2[k * D + t];
        x = a2;
    }
    float s = blockSum<256>(x, sbuf);
    float mean = s * (1.f / 128.f);
    float xm = (t < D) ? (x - mean) : 0.f;
    float var = blockSum<256>(xm * xm, sbuf) * (1.f / 128.f);
    if (t < D) high_out[c * D + t] = xm * rsqrtf(var + 1e-5f) * lng[t] + lnb[t];
}

// ---------------- weight transpose + bf16 cast: Wt[w][n][k] ----------------

__global__ __launch_bounds__(256) void wt_kernel(
    const float* __restrict__ wq, const float* __restrict__ wk,
    const float* __restrict__ wv, const float* __restrict__ wskip,
    unsigned short* __restrict__ wt4) {
    __shared__ float tile[128][132];
    int w = blockIdx.x;
    const float* Wp = (w == 0) ? wq : (w == 1) ? wk : (w == 2) ? wv : wskip;
    int t = threadIdx.x;
    #pragma unroll
    for (int rep = 0; rep < 16; ++rep) {
        int f4 = rep * 256 + t;
        float4 v = ((const float4*)Wp)[f4];
        int f = f4 * 4;
        int k = f >> 7, n = f & 127;
        tile[k][n] = v.x; tile[k][n + 1] = v.y; tile[k][n + 2] = v.z; tile[k][n + 3] = v.w;
    }
    __syncthreads();
    unsigned short* out = wt4 + (size_t)w * 16384;
    #pragma unroll
    for (int rep = 0; rep < 16; ++rep) {
        int f4 = rep * 256 + t;
        int f = f4 * 4;
        int n = f >> 7, k = f & 127;
        ushort4 o;
        o.x = f2bf(tile[k][n]);
        o.y = f2bf(tile[k + 1][n]);
        o.z = f2bf(tile[k + 2][n]);
        o.w = f2bf(tile[k + 3][n]);
        *(ushort4*)(out + (size_t)n * 128 + k) = o;
    }
}

// ---------------- fused 4-weight MFMA projection ----------------

__global__ __launch_bounds__(256, 2) void proj4_kernel(
    const float* __restrict__ X,
    const unsigned short* __restrict__ Wt4,
    const float* __restrict__ bq, const float* __restrict__ bk,
    const float* __restrict__ bv, const float* __restrict__ bs,
    unsigned short* __restrict__ Yq, unsigned short* __restrict__ Yk,
    unsigned short* __restrict__ Yv, float* __restrict__ Yskip) {
    __shared__ short Xs[128 * 128];
    __shared__ short Ws[128 * 128];
    int t = threadIdx.x;
    int lane = t & 63, wid = t >> 6;
    const float* Xblk = X + (size_t)blockIdx.x * 128 * 128;

    #pragma unroll
    for (int rep = 0; rep < 16; ++rep) {
        int f4 = rep * 256 + t;
        float4 xv = ((const float4*)Xblk)[f4];
        int f = f4 * 4;
        int row = f >> 7, k = f & 127;
        unsigned p0 = (unsigned)f2bf(xv.x) | ((unsigned)f2bf(xv.y) << 16);
        unsigned p1 = (unsigned)f2bf(xv.z) | ((unsigned)f2bf(xv.w) << 16);
        int eidx = (row * 128 + k) ^ ((row & 7) << 3);
        *(uint2*)(&Xs[eidx]) = make_uint2(p0, p1);
    }

    const float* Bs_[4] = {bq, bk, bv, bs};
    int lr = lane & 15, lg = lane >> 4;
    int rbase = (wid >> 1) * 64, cbase = (wid & 1) * 64;
    int orow0 = blockIdx.x * 128 + rbase;

    for (int w = 0; w < 4; ++w) {
        __syncthreads();
        const uint2* Wsrc = (const uint2*)(Wt4 + (size_t)w * 16384);
        #pragma unroll
        for (int rep = 0; rep < 16; ++rep) {
            int e4 = rep * 256 + t;
            uint2 d2 = Wsrc[e4];
            int f = e4 * 4;
            int n = f >> 7, k = f & 127;
            *(uint2*)(&Ws[(n * 128 + k) ^ ((n & 7) << 3)]) = d2;
        }
        __syncthreads();

        f32x4 acc[4][4] = {};
        #pragma unroll
        for (int ks = 0; ks < 4; ++ks) {
            int k0 = ks * 32 + lg * 8;
            bf16x8 a[4], b[4];
            #pragma unroll
            for (int m = 0; m < 4; ++m) {
                int row = rbase + m * 16 + lr;
                a[m] = *(const bf16x8*)(&Xs[(row * 128 + k0) ^ ((row & 7) << 3)]);
            }
            #pragma unroll
            for (int n = 0; n < 4; ++n) {
                int col = cbase + n * 16 + lr;
                b[n] = *(const bf16x8*)(&Ws[(col * 128 + k0) ^ ((col & 7) << 3)]);
            }
            #pragma unroll
            for (int m = 0; m < 4; ++m)
                #pragma unroll
                for (int n = 0; n < 4; ++n)
                    acc[m][n] = __builtin_amdgcn_mfma_f32_16x16x32_bf16(a[m], b[n], acc[m][n], 0, 0, 0);
        }

        const float* Bb = Bs_[w];
        if (w < 3) {
            unsigned short* Y = (w == 0) ? Yq : (w == 1) ? Yk : Yv;
            #pragma unroll
            for (int n = 0; n < 4; ++n) {
                int col = cbase + n * 16 + lr;
                float bias = Bb[col];
                #pragma unroll
                for (int m = 0; m < 4; ++m)
                    #pragma unroll
                    for (int j = 0; j < 4; ++j) {
                        int row = orow0 + m * 16 + lg * 4 + j;
                        Y[(size_t)row * 128 + col] = f2bf(acc[m][n][j] + bias);
                    }
            }
        } else {
            #pragma unroll
            for (int n = 0; n < 4; ++n) {
                int col = cbase + n * 16 + lr;
                float bias = Bb[col];
                #pragma unroll
                for (int m = 0; m < 4; ++m)
                    #pragma unroll
                    for (int j = 0; j < 4; ++j) {
                        int row = orow0 + m * 16 + lg * 4 + j;
                        Yskip[(size_t)row * 128 + col] = acc[m][n][j] + bias;
                    }
            }
        }
    }
}

// ---------------- per-cell V transpose: v[c][g][d] -> vt[c][d][g] ----------------

__global__ __launch_bounds__(256) void vt_kernel(const unsigned short* __restrict__ v,
                                                 unsigned short* __restrict__ vt) {
    __shared__ unsigned short tile[128][130];
    int c = blockIdx.x;
    size_t cb = (size_t)c * 32768;
    int t = threadIdx.x;
    for (int half = 0; half < 2; ++half) {
        __syncthreads();
        const unsigned* src = (const unsigned*)(v + cb + (size_t)half * 16384);
        #pragma unroll
        for (int i = 0; i < 32; ++i) {
            int f2 = i * 256 + t;
            unsigned u = src[f2];
            int g = f2 >> 6, d2 = f2 & 63;
            *(unsigned*)&tile[g][2 * d2] = u;
        }
        __syncthreads();
        #pragma unroll
        for (int i = 0; i < 32; ++i) {
            int f2 = i * 256 + t;
            int d = f2 >> 6, gp = f2 & 63;
            unsigned u = (unsigned)tile[2 * gp][d] | ((unsigned)tile[2 * gp + 1][d] << 16);
            ((unsigned*)(vt + cb + (size_t)d * 256 + half * 128))[gp] = u;
        }
    }
}

// ---------------- dense masked attention (MFMA) + skip + LayerNorm ----------------
// block = cell, wave = head. Swapped operands: S^T = K@Q^T, O^T = V^T@P^T.
// LDS: cnt4 32KB (swizzled) + P 4x8KB (swizzled) + obuf 8KB (swizzled) = 72KB

__global__ __launch_bounds__(256, 2) void attn_dense_kernel(
    const unsigned short* __restrict__ q, const unsigned short* __restrict__ k,
    const unsigned short* __restrict__ vt,
    const unsigned* __restrict__ cnt4,
    const float* __restrict__ lng, const float* __restrict__ lnb,
    float* __restrict__ outp) {
    extern __shared__ char smem[];
    unsigned* cntL = (unsigned*)smem;                       // 8192 words
    unsigned short* Pl = (unsigned short*)(smem + 32768);   // 4 x 4096 shorts
    float* obuf = (float*)(smem + 65536);                   // 16 x 128 f32
    int c = blockIdx.x;
    int t = threadIdx.x;
    int lane = t & 63, h = t >> 6;
    int lr = lane & 15, lg = lane >> 4;
    size_t cb = (size_t)c * 32768;

    // stage counts -> LDS (bank-swizzled within each 32-word row)
    #pragma unroll
    for (int i = 0; i < 32; ++i) {
        int idx = i * 256 + t;
        unsigned w = cnt4[idx];
        int dst = idx >> 5, w8 = idx & 31;
        cntL[dst * 32 + (w8 ^ (dst & 31))] = w;
    }

    // K fragments: A[row=src][k=hd], 16 src tiles (kept in regs for all dst tiles)
    bf16x8 kf[16];
    #pragma unroll
    for (int n = 0; n < 16; ++n)
        kf[n] = *(const bf16x8*)(k + cb + (size_t)(n * 16 + lr) * 128 + h * 32 + lg * 8);
    // V^T fragments: A[row=hd_local][k=src], [hd-tile][src-chunk]
    bf16x8 vf[2][8];
    #pragma unroll
    for (int ht = 0; ht < 2; ++ht)
        #pragma unroll
        for (int m = 0; m < 8; ++m)
            vf[ht][m] = *(const bf16x8*)(vt + cb + (size_t)(h * 32 + ht * 16 + lr) * 256 + m * 32 + lg * 8);

    __syncthreads();   // cntL ready

    unsigned short* Pw = Pl + h * 4096;
    const float scale = 0.17677669529663687f;   // 1/sqrt(32)

    for (int tile = 0; tile < 16; ++tile) {
        // Q b-fragment for this dst tile: B[k=hd][col=dst]
        bf16x8 qf = *(const bf16x8*)(q + cb + (size_t)(tile * 16 + lr) * 128 + h * 32 + lg * 8);

        // S^T: per lane holds (src = 16n+4lg+j, dst = 16*tile+lr)
        f32x4 s[16];
        const f32x4 z = {0.f, 0.f, 0.f, 0.f};
        #pragma unroll
        for (int n = 0; n < 16; ++n)
            s[n] = __builtin_amdgcn_mfma_f32_16x16x32_bf16(kf[n], qf, z, 0, 0, 0);

        int dst = tile * 16 + lr;
        // mask + scale + max
        unsigned cw[16];
        float m = -1e30f;
        #pragma unroll
        for (int n = 0; n < 16; ++n) {
            int w8 = 2 * n + (lg >> 1);
            unsigned w = cntL[dst * 32 + (w8 ^ (dst & 31))];
            cw[n] = (w >> (16 * (lg & 1))) & 0xFFFFu;
            #pragma unroll
            for (int j = 0; j < 4; ++j) {
                float val = s[n][j] * scale;
                s[n][j] = val;
                if ((cw[n] >> (4 * j)) & 15) m = fmaxf(m, val);
            }
        }
        m = fmaxf(m, __shfl_xor(m, 16));
        m = fmaxf(m, __shfl_xor(m, 32));
        // exp with multiplicity
        float den = 0.f;
        #pragma unroll
        for (int n = 0; n < 16; ++n) {
            #pragma unroll
            for (int j = 0; j < 4; ++j) {
                int cnt = (cw[n] >> (4 * j)) & 15;
                float e = cnt ? (float)cnt * expf(s[n][j] - m) : 0.f;
                s[n][j] = e;
                den += e;
            }
        }
        den += __shfl_xor(den, 16);
        den += __shfl_xor(den, 32);
        float inv = den > 0.f ? 1.f / den : 0.f;
        // pack P -> LDS (P[dst=lr][src], XOR-swizzled)
        #pragma unroll
        for (int n = 0; n < 16; ++n) {
            unsigned lo = (unsigned)f2bf(s[n][0] * inv) | ((unsigned)f2bf(s[n][1] * inv) << 16);
            unsigned hi = (unsigned)f2bf(s[n][2] * inv) | ((unsigned)f2bf(s[n][3] * inv) << 16);
            int e = (16 * n + 4 * lg) ^ (8 * (lr & 7));
            *(uint2*)(Pw + lr * 256 + e) = make_uint2(lo, hi);
        }
        // PV: O^T[hd][dst]
        f32x4 o[2] = {};
        #pragma unroll
        for (int m2 = 0; m2 < 8; ++m2) {
            int e = (32 * m2 + 8 * lg) ^ (8 * (lr & 7));
            bf16x8 pf = *(const bf16x8*)(Pw + lr * 256 + e);
            o[0] = __builtin_amdgcn_mfma_f32_16x16x32_bf16(vf[0][m2], pf, o[0], 0, 0, 0);
            o[1] = __builtin_amdgcn_mfma_f32_16x16x32_bf16(vf[1][m2], pf, o[1], 0, 0, 0);
        }
        // write O to obuf (gene=lr, d swizzled by gene)
        #pragma unroll
        for (int ht = 0; ht < 2; ++ht)
            #pragma unroll
            for (int j = 0; j < 4; ++j) {
                int d = h * 32 + ht * 16 + lg * 4 + j;
                obuf[lr * 128 + (d ^ (4 * (lr & 7)))] = o[ht][j];
            }
        __syncthreads();

        // skip + LayerNorm for these 16 genes (16 threads per gene)
        {
            int gl = t >> 4, sub = t & 15;
            int g = tile * 16 + gl;
            int swz = 4 * (gl & 7);
            float4 oa = *(float4*)(obuf + gl * 128 + ((sub * 8) ^ swz));
            float4 ob = *(float4*)(obuf + gl * 128 + ((sub * 8 + 4) ^ swz));
            const float* skp = outp + cb + (size_t)g * 128 + sub * 8;
            float4 sa = *(const float4*)(skp);
            float4 sb = *(const float4*)(skp + 4);
            float x[8] = {oa.x + sa.x, oa.y + sa.y, oa.z + sa.z, oa.w + sa.w,
                          ob.x + sb.x, ob.y + sb.y, ob.z + sb.z, ob.w + sb.w};
            float sm = 0.f;
            #pragma unroll
            for (int i = 0; i < 8; ++i) sm += x[i];
            sm += __shfl_xor(sm, 1); sm += __shfl_xor(sm, 2);
            sm += __shfl_xor(sm, 4); sm += __shfl_xor(sm, 8);
            float mean = sm * (1.f / 128.f);
            float vv = 0.f;
            #pragma unroll
            for (int i = 0; i < 8; ++i) { x[i] -= mean; vv += x[i] * x[i]; }
            vv += __shfl_xor(vv, 1); vv += __shfl_xor(vv, 2);
            vv += __shfl_xor(vv, 4); vv += __shfl_xor(vv, 8);
            float rs = rsqrtf(vv * (1.f / 128.f) + 1e-5f);
            float4 ga = *(const float4*)(lng + sub * 8);
            float4 gb = *(const float4*)(lng + sub * 8 + 4);
            float4 ba = *(const float4*)(lnb + sub * 8);
            float4 bb = *(const float4*)(lnb + sub * 8 + 4);
            float* op = outp + cb + (size_t)g * 128 + sub * 8;
            float4 r1 = {x[0] * rs * ga.x + ba.x, x[1] * rs * ga.y + ba.y,
                         x[2] * rs * ga.z + ba.z, x[3] * rs * ga.w + ba.w};
            float4 r2 = {x[4] * rs * gb.x + bb.x, x[5] * rs * gb.y + bb.y,
                         x[6] * rs * gb.z + bb.z, x[7] * rs * gb.w + bb.w};
            *(float4*)(op) = r1;
            *(float4*)(op + 4) = r2;
        }
        __syncthreads();
    }
}

// ---------------- gene aggregation ----------------

__global__ __launch_bounds__(128) void gene_agg_kernel(
    const float* __restrict__ low_out,
    const float* __restrict__ agg_w, const float* __restrict__ agg_b,
    float* __restrict__ gene_agg) {
    int c = blockIdx.x, d = threadIdx.x;
    const float* base = low_out + (size_t)c * N_GENES * D;
    float s = 0.f;
    for (int g = 0; g < N_GENES; ++g) s += base[g * D + d];
    __shared__ float m[D];
    m[d] = s * (1.f / 256.f);
    __syncthreads();
    float acc = agg_b[d];
    for (int k = 0; k < D; ++k) acc += m[k] * agg_w[k * D + d];
    gene_agg[c * D + d] = gelu_exact(acc);
}

// ---------------- cross gating + high LayerNorm ----------------

__global__ __launch_bounds__(128) void cross_kernel(
    const float* __restrict__ high_emb, const float* __restrict__ high_out,
    const float* __restrict__ gene_agg,
    const float* __restrict__ cw, const float* __restrict__ cb,
    const float* __restrict__ nhg, const float* __restrict__ nhb,
    float* __restrict__ high_new, float* __restrict__ low_cross) {
    int c = blockIdx.x, d = threadIdx.x;
    __shared__ float ho[D], ga[D];
    __shared__ float sbuf[2];
    ho[d] = high_out[c * D + d];
    ga[d] = gene_agg[c * D + d];
    __syncthreads();
    float q1 = cb[0 * D + d], k1 = cb[1 * D + d], v1 = cb[2 * D + d];
    float q2 = cb[3 * D + d], k2 = cb[4 * D + d], v2 = cb[5 * D + d];
    for (int k = 0; k < D; ++k) {
        float hv = ho[k], gv = ga[k];
        q1 += hv * cw[0 * 16384 + k * D + d];
        k1 += gv * cw[1 * 16384 + k * D + d];
        v1 += gv * cw[2 * 16384 + k * D + d];
        q2 += gv * cw[3 * 16384 + k * D + d];
        k2 += hv * cw[4 * 16384 + k * D + d];
        v2 += hv * cw[5 * 16384 + k * D + d];
    }
    const float scale = 0.08838834764831845f;
    float s1 = blockSum<128>(q1 * k1, sbuf);
    float s2 = blockSum<128>(q2 * k2, sbuf);
    float hc = (1.f / (1.f + expf(-s1 * scale))) * v1;
    float lc = (1.f / (1.f + expf(-s2 * scale))) * v2;
    low_cross[c * D + d] = lc;
    float x = high_emb[c * D + d] + ho[d] + hc;
    float sm = blockSum<128>(x, sbuf);
    float mean = sm * (1.f / 128.f);
    float xm = x - mean;
    float var = blockSum<128>(xm * xm, sbuf) * (1.f / 128.f);
    high_new[c * D + d] = xm * rsqrtf(var + 1e-5f) * nhg[d] + nhb[d];
}

// ---------------- final low LayerNorm ----------------

__global__ __launch_bounds__(128) void low_final_kernel(
    const float* __restrict__ low_emb, const float* __restrict__ low_cross,
    const float* __restrict__ nlg, const float* __restrict__ nlb,
    float* __restrict__ out) {
    int cg = blockIdx.x;
    int c = cg >> 8;
    int d = threadIdx.x;
    size_t idx = (size_t)cg * D + d;
    float x = low_emb[idx] + out[idx] + low_cross[c * D + d];
    __shared__ float sbuf[2];
    float s = blockSum<128>(x, sbuf);
    float mean = s * (1.f / 128.f);
    float xm = x - mean;
    float var = blockSum<128>(xm * xm, sbuf) * (1.f / 128.f);
    out[idx] = xm * rsqrtf(var + 1e-5f) * nlg[d] + nlb[d];
}

// ---------------- launch ----------------

extern "C" void kernel_launch(void* const* d_in, const int* in_sizes, int n_in,
                              void* d_out, int out_size, void* d_ws, size_t ws_size,
                              hipStream_t stream) {
    const float* high_emb = (const float*)d_in[0];
    const float* low_emb  = (const float*)d_in[1];
    const int*   sp       = (const int*)d_in[2];
    const int*   grn      = (const int*)d_in[3];
    const float* gin_w1   = (const float*)d_in[4];
    const float* gin_b1   = (const float*)d_in[5];
    const float* gin_w2   = (const float*)d_in[6];
    const float* gin_b2   = (const float*)d_in[7];
    const float* gin_eps  = (const float*)d_in[8];
    const float* gin_lng  = (const float*)d_in[9];
    const float* gin_lnb  = (const float*)d_in[10];
    const float* tc_wq    = (const float*)d_in[11];
    const float* tc_bq    = (const float*)d_in[12];
    const float* tc_wk    = (const float*)d_in[13];
    const float* tc_bk    = (const float*)d_in[14];
    const float* tc_wv    = (const float*)d_in[15];
    const float* tc_bv    = (const float*)d_in[16];
    const float* tc_wskip = (const float*)d_in[17];
    const float* tc_bskip = (const float*)d_in[18];
    const float* tc_lng   = (const float*)d_in[19];
    const float* tc_lnb   = (const float*)d_in[20];
    const float* cross_w  = (const float*)d_in[21];
    const float* cross_b  = (const float*)d_in[22];
    const float* agg_w    = (const float*)d_in[23];
    const float* agg_b    = (const float*)d_in[24];
    const float* nh_g     = (const float*)d_in[25];
    const float* nh_b     = (const float*)d_in[26];
    const float* nl_g     = (const float*)d_in[27];
    const float* nl_b     = (const float*)d_in[28];

    float* out = (float*)d_out;
    float* out_high = out;
    float* out_low  = out + N_CELLS * D;

    const size_t LOW_N = (size_t)N_CELLS * N_GENES * D;   // 16777216

    unsigned short* q_b = (unsigned short*)d_ws;
    unsigned short* k_b = q_b + LOW_N;
    unsigned short* v_b = k_b + LOW_N;
    unsigned short* vt_b = v_b + LOW_N;
    float* ws_high_out  = (float*)(vt_b + LOW_N);
    float* ws_gene_agg  = ws_high_out + N_CELLS * D;
    float* ws_low_cross = ws_gene_agg + N_CELLS * D;
    unsigned short* wt4 = (unsigned short*)(ws_low_cross + N_CELLS * D);
    unsigned* cnt4 = (unsigned*)(wt4 + 4 * 128 * 128);
    int* sp_off  = (int*)(cnt4 + 8192);
    int* sp_src  = sp_off + 516;

    // prep: spatial CSR, GRN counts, weight transpose
    sp_csr_kernel<<<1, 512, 0, stream>>>(sp, sp_off, sp_src);
    hipMemsetAsync(cnt4, 0, 8192 * sizeof(unsigned), stream);
    cnt_build_kernel<<<E_GRN / 256, 256, 0, stream>>>(grn, cnt4);
    wt_kernel<<<4, 256, 0, stream>>>(tc_wq, tc_wk, tc_wv, tc_wskip, wt4);

    // high level GIN
    gin_mlp_kernel<<<N_CELLS, 256, 0, stream>>>(high_emb, sp_off, sp_src, gin_eps,
        gin_w1, gin_b1, gin_w2, gin_b2, gin_lng, gin_lnb, ws_high_out);

    // projections (MFMA) -> q,k,v bf16 + skip f32 (in out_low)
    proj4_kernel<<<N_CELLS * N_GENES / 128, 256, 0, stream>>>(
        low_emb, wt4, tc_bq, tc_bk, tc_bv, tc_bskip, q_b, k_b, v_b, out_low);

    // per-cell V transpose for PV A-fragments
    vt_kernel<<<N_CELLS, 256, 0, stream>>>(v_b, vt_b);

    // dense masked attention + skip + LN
    attn_dense_kernel<<<N_CELLS, 256, 73728, stream>>>(
        q_b, k_b, vt_b, cnt4, tc_lng, tc_lnb, out_low);

    // gene aggregation
    gene_agg_kernel<<<N_CELLS, 128, 0, stream>>>(out_low, agg_w, agg_b, ws_gene_agg);

    // cross gating + high LN
    cross_kernel<<<N_CELLS, 128, 0, stream>>>(high_emb, ws_high_out, ws_gene_agg,
        cross_w, cross_b, nh_g, nh_b, out_high, ws_low_cross);

    // final low LN
    low_final_kernel<<<N_CELLS * N_GENES, 128, 0, stream>>>(
        low_emb, ws_low_cross, nl_g, nl_b, out_low);
}

// Round 6
// 561.826 us; speedup vs baseline: 1.2392x; 1.0972x over previous
//
#include <hip/hip_runtime.h>
#include <hip/hip_bf16.h>
#include <math.h>

#define N_CELLS 512
#define N_GENES 256
#define D 128
#define HEADS 4
#define HD 32
#define E_SP 8192
#define E_GRN 2048

typedef __attribute__((ext_vector_type(8))) short bf16x8;
typedef __attribute__((ext_vector_type(4))) float f32x4;

// ---------------- utility ----------------

__device__ __forceinline__ float gelu_exact(float x) {
    return 0.5f * x * (1.0f + erff(x * 0.70710678118654752f));
}

__device__ __forceinline__ unsigned short f2bf(float f) {
    unsigned u = __float_as_uint(f);
    return (unsigned short)((u + 0x7FFFu + ((u >> 16) & 1u)) >> 16);
}

template<int NT>
__device__ __forceinline__ float blockSum(float v, float* sbuf) {
    #pragma unroll
    for (int off = 32; off > 0; off >>= 1) v += __shfl_down(v, off, 64);
    int lane = threadIdx.x & 63, wid = threadIdx.x >> 6;
    __syncthreads();
    if (lane == 0) sbuf[wid] = v;
    __syncthreads();
    float r = 0.f;
    #pragma unroll
    for (int i = 0; i < NT / 64; ++i) r += sbuf[i];
    return r;
}

// ---------------- spatial CSR build (512 bins) ----------------

__global__ __launch_bounds__(512) void sp_csr_kernel(const int* __restrict__ sp,
                                                     int* __restrict__ sp_off,
                                                     int* __restrict__ sp_src) {
    __shared__ int cnt[512];
    __shared__ int scan[512];
    __shared__ int cur[512];
    int t = threadIdx.x;
    cnt[t] = 0;
    __syncthreads();
    for (int e = t; e < E_SP; e += 512) atomicAdd(&cnt[sp[E_SP + e]], 1);
    __syncthreads();
    scan[t] = cnt[t];
    __syncthreads();
    #pragma unroll
    for (int s = 1; s < 512; s <<= 1) {
        int v = (t >= s) ? scan[t - s] : 0;
        __syncthreads();
        scan[t] += v;
        __syncthreads();
    }
    int excl = scan[t] - cnt[t];
    sp_off[t] = excl;
    if (t == 511) sp_off[512] = scan[511];
    cur[t] = excl;
    __syncthreads();
    for (int e = t; e < E_SP; e += 512) {
        int dst = sp[E_SP + e];
        int pos = atomicAdd(&cur[dst], 1);
        sp_src[pos] = sp[e];
    }
}

// ---------------- GRN multiplicity counts, 4-bit packed: cnt4[dst*32 + src/8] ----------------

__global__ void cnt_build_kernel(const int* __restrict__ grn, unsigned* __restrict__ cnt4) {
    int e = blockIdx.x * 256 + threadIdx.x;
    int src = grn[e], dst = grn[E_GRN + e];
    atomicAdd(&cnt4[dst * 32 + (src >> 3)], 1u << (4 * (src & 7)));
}

// ---------------- GIN MLP with inline CSR gather ----------------

__global__ __launch_bounds__(256) void gin_mlp_kernel(
    const float* __restrict__ high,
    const int* __restrict__ sp_off, const int* __restrict__ sp_src,
    const float* __restrict__ eps,
    const float* __restrict__ w1, const float* __restrict__ b1,
    const float* __restrict__ w2, const float* __restrict__ b2,
    const float* __restrict__ lng, const float* __restrict__ lnb,
    float* __restrict__ high_out) {
    int c = blockIdx.x;
    int t = threadIdx.x;
    __shared__ float h[D];
    __shared__ float h1[2 * D];
    __shared__ float sbuf[4];
    if (t < D) {
        float acc = 0.f;
        int off = sp_off[c], end = sp_off[c + 1];
        for (int i = off; i < end; ++i) acc += high[(size_t)sp_src[i] * D + t];
        h[t] = (1.f + eps[0]) * high[c * D + t] + acc;
    }
    __syncthreads();
    float a = b1[t];
    for (int k = 0; k < D; ++k) a += h[k] * w1[k * 256 + t];
    h1[t] = gelu_exact(a);
    __syncthreads();
    float x = 0.f;
    if (t < D) {
        float a2 = b2[t];
        for (int k = 0; k < 256; ++k) a2 += h1[k] * w2[k * D + t];
        x = a2;
    }
    float s = blockSum<256>(x, sbuf);
    float mean = s * (1.f / 128.f);
    float xm = (t < D) ? (x - mean) : 0.f;
    float var = blockSum<256>(xm * xm, sbuf) * (1.f / 128.f);
    if (t < D) high_out[c * D + t] = xm * rsqrtf(var + 1e-5f) * lng[t] + lnb[t];
}

// ---------------- weight transpose + bf16 cast: Wt[w][n][k] ----------------

__global__ __launch_bounds__(256) void wt_kernel(
    const float* __restrict__ wq, const float* __restrict__ wk,
    const float* __restrict__ wv, const float* __restrict__ wskip,
    unsigned short* __restrict__ wt4) {
    __shared__ float tile[128][132];
    int w = blockIdx.x;
    const float* Wp = (w == 0) ? wq : (w == 1) ? wk : (w == 2) ? wv : wskip;
    int t = threadIdx.x;
    #pragma unroll
    for (int rep = 0; rep < 16; ++rep) {
        int f4 = rep * 256 + t;
        float4 v = ((const float4*)Wp)[f4];
        int f = f4 * 4;
        int k = f >> 7, n = f & 127;
        tile[k][n] = v.x; tile[k][n + 1] = v.y; tile[k][n + 2] = v.z; tile[k][n + 3] = v.w;
    }
    __syncthreads();
    unsigned short* out = wt4 + (size_t)w * 16384;
    #pragma unroll
    for (int rep = 0; rep < 16; ++rep) {
        int f4 = rep * 256 + t;
        int f = f4 * 4;
        int n = f >> 7, k = f & 127;
        ushort4 o;
        o.x = f2bf(tile[k][n]);
        o.y = f2bf(tile[k + 1][n]);
        o.z = f2bf(tile[k + 2][n]);
        o.w = f2bf(tile[k + 3][n]);
        *(ushort4*)(out + (size_t)n * 128 + k) = o;
    }
}

// ---------------- fused 4-weight MFMA projection ----------------

__global__ __launch_bounds__(256, 2) void proj4_kernel(
    const float* __restrict__ X,
    const unsigned short* __restrict__ Wt4,
    const float* __restrict__ bq, const float* __restrict__ bk,
    const float* __restrict__ bv, const float* __restrict__ bs,
    unsigned short* __restrict__ Yq, unsigned short* __restrict__ Yk,
    unsigned short* __restrict__ Yv, float* __restrict__ Yskip) {
    __shared__ short Xs[128 * 128];
    __shared__ short Ws[128 * 128];
    int t = threadIdx.x;
    int lane = t & 63, wid = t >> 6;
    const float* Xblk = X + (size_t)blockIdx.x * 128 * 128;

    #pragma unroll
    for (int rep = 0; rep < 16; ++rep) {
        int f4 = rep * 256 + t;
        float4 xv = ((const float4*)Xblk)[f4];
        int f = f4 * 4;
        int row = f >> 7, k = f & 127;
        unsigned p0 = (unsigned)f2bf(xv.x) | ((unsigned)f2bf(xv.y) << 16);
        unsigned p1 = (unsigned)f2bf(xv.z) | ((unsigned)f2bf(xv.w) << 16);
        int eidx = (row * 128 + k) ^ ((row & 7) << 3);
        *(uint2*)(&Xs[eidx]) = make_uint2(p0, p1);
    }

    const float* Bs_[4] = {bq, bk, bv, bs};
    int lr = lane & 15, lg = lane >> 4;
    int rbase = (wid >> 1) * 64, cbase = (wid & 1) * 64;
    int orow0 = blockIdx.x * 128 + rbase;

    for (int w = 0; w < 4; ++w) {
        __syncthreads();
        const uint2* Wsrc = (const uint2*)(Wt4 + (size_t)w * 16384);
        #pragma unroll
        for (int rep = 0; rep < 16; ++rep) {
            int e4 = rep * 256 + t;
            uint2 d2 = Wsrc[e4];
            int f = e4 * 4;
            int n = f >> 7, k = f & 127;
            *(uint2*)(&Ws[(n * 128 + k) ^ ((n & 7) << 3)]) = d2;
        }
        __syncthreads();

        f32x4 acc[4][4] = {};
        #pragma unroll
        for (int ks = 0; ks < 4; ++ks) {
            int k0 = ks * 32 + lg * 8;
            bf16x8 a[4], b[4];
            #pragma unroll
            for (int m = 0; m < 4; ++m) {
                int row = rbase + m * 16 + lr;
                a[m] = *(const bf16x8*)(&Xs[(row * 128 + k0) ^ ((row & 7) << 3)]);
            }
            #pragma unroll
            for (int n = 0; n < 4; ++n) {
                int col = cbase + n * 16 + lr;
                b[n] = *(const bf16x8*)(&Ws[(col * 128 + k0) ^ ((col & 7) << 3)]);
            }
            #pragma unroll
            for (int m = 0; m < 4; ++m)
                #pragma unroll
                for (int n = 0; n < 4; ++n)
                    acc[m][n] = __builtin_amdgcn_mfma_f32_16x16x32_bf16(a[m], b[n], acc[m][n], 0, 0, 0);
        }

        const float* Bb = Bs_[w];
        if (w < 3) {
            unsigned short* Y = (w == 0) ? Yq : (w == 1) ? Yk : Yv;
            #pragma unroll
            for (int n = 0; n < 4; ++n) {
                int col = cbase + n * 16 + lr;
                float bias = Bb[col];
                #pragma unroll
                for (int m = 0; m < 4; ++m)
                    #pragma unroll
                    for (int j = 0; j < 4; ++j) {
                        int row = orow0 + m * 16 + lg * 4 + j;
                        Y[(size_t)row * 128 + col] = f2bf(acc[m][n][j] + bias);
                    }
            }
        } else {
            #pragma unroll
            for (int n = 0; n < 4; ++n) {
                int col = cbase + n * 16 + lr;
                float bias = Bb[col];
                #pragma unroll
                for (int m = 0; m < 4; ++m)
                    #pragma unroll
                    for (int j = 0; j < 4; ++j) {
                        int row = orow0 + m * 16 + lg * 4 + j;
                        Yskip[(size_t)row * 128 + col] = acc[m][n][j] + bias;
                    }
            }
        }
    }
}

// ---------------- per-cell V transpose: v[c][g][d] -> vt[c][d][g] ----------------

__global__ __launch_bounds__(256) void vt_kernel(const unsigned short* __restrict__ v,
                                                 unsigned short* __restrict__ vt) {
    __shared__ unsigned short tile[128][130];
    int c = blockIdx.x;
    size_t cb = (size_t)c * 32768;
    int t = threadIdx.x;
    for (int half = 0; half < 2; ++half) {
        __syncthreads();
        const unsigned* src = (const unsigned*)(v + cb + (size_t)half * 16384);
        #pragma unroll
        for (int i = 0; i < 32; ++i) {
            int f2 = i * 256 + t;
            unsigned u = src[f2];
            int g = f2 >> 6, d2 = f2 & 63;
            *(unsigned*)&tile[g][2 * d2] = u;
        }
        __syncthreads();
        #pragma unroll
        for (int i = 0; i < 32; ++i) {
            int f2 = i * 256 + t;
            int d = f2 >> 6, gp = f2 & 63;
            unsigned u = (unsigned)tile[2 * gp][d] | ((unsigned)tile[2 * gp + 1][d] << 16);
            ((unsigned*)(vt + cb + (size_t)d * 256 + half * 128))[gp] = u;
        }
    }
}

// ---------------- dense masked attention (MFMA) + skip + LayerNorm ----------------
// block = cell, wave = head. LDS (136KB dyn): K 64KB (swz) | cnt 32KB (swz) | P 4x8KB (swz) | obuf 8KB
// Only s[16] stays register-resident; K frags from LDS, V^T frags from global (L2-resident).

__global__ __launch_bounds__(256, 1) void attn_dense_kernel(
    const unsigned short* __restrict__ q, const unsigned short* __restrict__ k,
    const unsigned short* __restrict__ vt,
    const unsigned* __restrict__ cnt4,
    const float* __restrict__ lng, const float* __restrict__ lnb,
    float* __restrict__ outp) {
    extern __shared__ char smem[];
    unsigned* cntL = (unsigned*)(smem + 65536);             // 8192 words
    unsigned short* Pl = (unsigned short*)(smem + 98304);   // 4 x 4096 shorts
    float* obuf = (float*)(smem + 131072);                  // 16 x 128 f32
    int c = blockIdx.x;
    int t = threadIdx.x;
    int lane = t & 63, h = t >> 6;
    int lr = lane & 15, lg = lane >> 4;
    int gl = t >> 4, sub = t & 15;
    size_t cb = (size_t)c * 32768;

    // stage K -> LDS, 16B granules, XOR swizzle byte ^= (row&7)<<4
    {
        const uint4* src = (const uint4*)(k + cb);
        #pragma unroll
        for (int i = 0; i < 16; ++i) {
            int f4 = i * 256 + t;
            uint4 d = src[f4];
            int row = f4 >> 4, c16 = f4 & 15;
            *(uint4*)(smem + row * 256 + ((c16 * 16) ^ ((row & 7) << 4))) = d;
        }
    }
    // stage counts -> LDS (bank-swizzled within each 32-word row)
    #pragma unroll
    for (int i = 0; i < 32; ++i) {
        int idx = i * 256 + t;
        unsigned w = cnt4[idx];
        int dst2 = idx >> 5, w8 = idx & 31;
        cntL[dst2 * 32 + (w8 ^ (dst2 & 31))] = w;
    }
    __syncthreads();

    unsigned short* Pw = Pl + h * 4096;
    const float scale = 0.17677669529663687f;   // 1/sqrt(32)
    int kcol = h * 64 + lg * 16;                // K col byte offset (pre-swizzle)
    int kswz = (lr & 7) << 4;

    for (int tile = 0; tile < 16; ++tile) {
        // prefetch skip row chunk for LN phase (consumed after PV)
        const float* skp = outp + cb + (size_t)(tile * 16 + gl) * 128 + sub * 8;
        float4 sa = *(const float4*)(skp);
        float4 sb = *(const float4*)(skp + 4);

        // Q b-fragment: B[k=hd][col=dst]
        bf16x8 qf = *(const bf16x8*)(q + cb + (size_t)(tile * 16 + lr) * 128 + h * 32 + lg * 8);

        // S^T = K @ Q^T : per lane (src = 16n+4lg+j, dst = 16*tile+lr)
        f32x4 s[16];
        const f32x4 z = {0.f, 0.f, 0.f, 0.f};
        #pragma unroll
        for (int n = 0; n < 16; ++n) {
            int row = n * 16 + lr;
            bf16x8 kf = *(const bf16x8*)(smem + row * 256 + (kcol ^ kswz));
            s[n] = __builtin_amdgcn_mfma_f32_16x16x32_bf16(kf, qf, z, 0, 0, 0);
        }

        int dst = tile * 16 + lr;
        // mask + scale + max
        unsigned cw[16];
        float m = -1e30f;
        #pragma unroll
        for (int n = 0; n < 16; ++n) {
            int w8 = 2 * n + (lg >> 1);
            unsigned w = cntL[dst * 32 + (w8 ^ (dst & 31))];
            cw[n] = (w >> (16 * (lg & 1))) & 0xFFFFu;
            #pragma unroll
            for (int j = 0; j < 4; ++j) {
                float val = s[n][j] * scale;
                s[n][j] = val;
                if ((cw[n] >> (4 * j)) & 15) m = fmaxf(m, val);
            }
        }
        m = fmaxf(m, __shfl_xor(m, 16));
        m = fmaxf(m, __shfl_xor(m, 32));
        // exp with multiplicity
        float den = 0.f;
        #pragma unroll
        for (int n = 0; n < 16; ++n) {
            #pragma unroll
            for (int j = 0; j < 4; ++j) {
                int cnt = (cw[n] >> (4 * j)) & 15;
                float e = cnt ? (float)cnt * expf(s[n][j] - m) : 0.f;
                s[n][j] = e;
                den += e;
            }
        }
        den += __shfl_xor(den, 16);
        den += __shfl_xor(den, 32);
        float inv = den > 0.f ? 1.f / den : 0.f;
        // pack P -> LDS (P[dst=lr][src], XOR-swizzled); wave-local buffer
        #pragma unroll
        for (int n = 0; n < 16; ++n) {
            unsigned lo = (unsigned)f2bf(s[n][0] * inv) | ((unsigned)f2bf(s[n][1] * inv) << 16);
            unsigned hi = (unsigned)f2bf(s[n][2] * inv) | ((unsigned)f2bf(s[n][3] * inv) << 16);
            int e = (16 * n + 4 * lg) ^ (8 * (lr & 7));
            *(uint2*)(Pw + lr * 256 + e) = make_uint2(lo, hi);
        }
        // PV: O^T[hd][dst], V^T fragments streamed from global (L2)
        f32x4 o[2] = {};
        #pragma unroll
        for (int m2 = 0; m2 < 8; ++m2) {
            int e = (32 * m2 + 8 * lg) ^ (8 * (lr & 7));
            bf16x8 pf = *(const bf16x8*)(Pw + lr * 256 + e);
            bf16x8 v0 = *(const bf16x8*)(vt + cb + (size_t)(h * 32 + lr) * 256 + m2 * 32 + lg * 8);
            bf16x8 v1 = *(const bf16x8*)(vt + cb + (size_t)(h * 32 + 16 + lr) * 256 + m2 * 32 + lg * 8);
            o[0] = __builtin_amdgcn_mfma_f32_16x16x32_bf16(v0, pf, o[0], 0, 0, 0);
            o[1] = __builtin_amdgcn_mfma_f32_16x16x32_bf16(v1, pf, o[1], 0, 0, 0);
        }
        // write O to obuf (gene=lr, d swizzled by gene)
        #pragma unroll
        for (int ht = 0; ht < 2; ++ht)
            #pragma unroll
            for (int j = 0; j < 4; ++j) {
                int d = h * 32 + ht * 16 + lg * 4 + j;
                obuf[lr * 128 + (d ^ (4 * (lr & 7)))] = o[ht][j];
            }
        __syncthreads();

        // skip + LayerNorm for these 16 genes (16 threads per gene)
        {
            int g = tile * 16 + gl;
            int swz = 4 * (gl & 7);
            float4 oa = *(float4*)(obuf + gl * 128 + ((sub * 8) ^ swz));
            float4 ob = *(float4*)(obuf + gl * 128 + ((sub * 8 + 4) ^ swz));
            float x[8] = {oa.x + sa.x, oa.y + sa.y, oa.z + sa.z, oa.w + sa.w,
                          ob.x + sb.x, ob.y + sb.y, ob.z + sb.z, ob.w + sb.w};
            float sm = 0.f;
            #pragma unroll
            for (int i = 0; i < 8; ++i) sm += x[i];
            sm += __shfl_xor(sm, 1); sm += __shfl_xor(sm, 2);
            sm += __shfl_xor(sm, 4); sm += __shfl_xor(sm, 8);
            float mean = sm * (1.f / 128.f);
            float vv = 0.f;
            #pragma unroll
            for (int i = 0; i < 8; ++i) { x[i] -= mean; vv += x[i] * x[i]; }
            vv += __shfl_xor(vv, 1); vv += __shfl_xor(vv, 2);
            vv += __shfl_xor(vv, 4); vv += __shfl_xor(vv, 8);
            float rs = rsqrtf(vv * (1.f / 128.f) + 1e-5f);
            float4 ga = *(const float4*)(lng + sub * 8);
            float4 gb = *(const float4*)(lng + sub * 8 + 4);
            float4 ba = *(const float4*)(lnb + sub * 8);
            float4 bb = *(const float4*)(lnb + sub * 8 + 4);
            float* op = outp + cb + (size_t)g * 128 + sub * 8;
            float4 r1 = {x[0] * rs * ga.x + ba.x, x[1] * rs * ga.y + ba.y,
                         x[2] * rs * ga.z + ba.z, x[3] * rs * ga.w + ba.w};
            float4 r2 = {x[4] * rs * gb.x + bb.x, x[5] * rs * gb.y + bb.y,
                         x[6] * rs * gb.z + bb.z, x[7] * rs * gb.w + bb.w};
            *(float4*)(op) = r1;
            *(float4*)(op + 4) = r2;
        }
        __syncthreads();
    }
}

// ---------------- gene aggregation ----------------

__global__ __launch_bounds__(128) void gene_agg_kernel(
    const float* __restrict__ low_out,
    const float* __restrict__ agg_w, const float* __restrict__ agg_b,
    float* __restrict__ gene_agg) {
    int c = blockIdx.x, d = threadIdx.x;
    const float* base = low_out + (size_t)c * N_GENES * D;
    float s = 0.f;
    for (int g = 0; g < N_GENES; ++g) s += base[g * D + d];
    __shared__ float m[D];
    m[d] = s * (1.f / 256.f);
    __syncthreads();
    float acc = agg_b[d];
    for (int k = 0; k < D; ++k) acc += m[k] * agg_w[k * D + d];
    gene_agg[c * D + d] = gelu_exact(acc);
}

// ---------------- cross gating + high LayerNorm ----------------

__global__ __launch_bounds__(128) void cross_kernel(
    const float* __restrict__ high_emb, const float* __restrict__ high_out,
    const float* __restrict__ gene_agg,
    const float* __restrict__ cw, const float* __restrict__ cb,
    const float* __restrict__ nhg, const float* __restrict__ nhb,
    float* __restrict__ high_new, float* __restrict__ low_cross) {
    int c = blockIdx.x, d = threadIdx.x;
    __shared__ float ho[D], ga[D];
    __shared__ float sbuf[2];
    ho[d] = high_out[c * D + d];
    ga[d] = gene_agg[c * D + d];
    __syncthreads();
    float q1 = cb[0 * D + d], k1 = cb[1 * D + d], v1 = cb[2 * D + d];
    float q2 = cb[3 * D + d], k2 = cb[4 * D + d], v2 = cb[5 * D + d];
    for (int k = 0; k < D; ++k) {
        float hv = ho[k], gv = ga[k];
        q1 += hv * cw[0 * 16384 + k * D + d];
        k1 += gv * cw[1 * 16384 + k * D + d];
        v1 += gv * cw[2 * 16384 + k * D + d];
        q2 += gv * cw[3 * 16384 + k * D + d];
        k2 += hv * cw[4 * 16384 + k * D + d];
        v2 += hv * cw[5 * 16384 + k * D + d];
    }
    const float scale = 0.08838834764831845f;
    float s1 = blockSum<128>(q1 * k1, sbuf);
    float s2 = blockSum<128>(q2 * k2, sbuf);
    float hc = (1.f / (1.f + expf(-s1 * scale))) * v1;
    float lc = (1.f / (1.f + expf(-s2 * scale))) * v2;
    low_cross[c * D + d] = lc;
    float x = high_emb[c * D + d] + ho[d] + hc;
    float sm = blockSum<128>(x, sbuf);
    float mean = sm * (1.f / 128.f);
    float xm = x - mean;
    float var = blockSum<128>(xm * xm, sbuf) * (1.f / 128.f);
    high_new[c * D + d] = xm * rsqrtf(var + 1e-5f) * nhg[d] + nhb[d];
}

// ---------------- final low LayerNorm ----------------

__global__ __launch_bounds__(128) void low_final_kernel(
    const float* __restrict__ low_emb, const float* __restrict__ low_cross,
    const float* __restrict__ nlg, const float* __restrict__ nlb,
    float* __restrict__ out) {
    int cg = blockIdx.x;
    int c = cg >> 8;
    int d = threadIdx.x;
    size_t idx = (size_t)cg * D + d;
    float x = low_emb[idx] + out[idx] + low_cross[c * D + d];
    __shared__ float sbuf[2];
    float s = blockSum<128>(x, sbuf);
    float mean = s * (1.f / 128.f);
    float xm = x - mean;
    float var = blockSum<128>(xm * xm, sbuf) * (1.f / 128.f);
    out[idx] = xm * rsqrtf(var + 1e-5f) * nlg[d] + nlb[d];
}

// ---------------- launch ----------------

extern "C" void kernel_launch(void* const* d_in, const int* in_sizes, int n_in,
                              void* d_out, int out_size, void* d_ws, size_t ws_size,
                              hipStream_t stream) {
    const float* high_emb = (const float*)d_in[0];
    const float* low_emb  = (const float*)d_in[1];
    const int*   sp       = (const int*)d_in[2];
    const int*   grn      = (const int*)d_in[3];
    const float* gin_w1   = (const float*)d_in[4];
    const float* gin_b1   = (const float*)d_in[5];
    const float* gin_w2   = (const float*)d_in[6];
    const float* gin_b2   = (const float*)d_in[7];
    const float* gin_eps  = (const float*)d_in[8];
    const float* gin_lng  = (const float*)d_in[9];
    const float* gin_lnb  = (const float*)d_in[10];
    const float* tc_wq    = (const float*)d_in[11];
    const float* tc_bq    = (const float*)d_in[12];
    const float* tc_wk    = (const float*)d_in[13];
    const float* tc_bk    = (const float*)d_in[14];
    const float* tc_wv    = (const float*)d_in[15];
    const float* tc_bv    = (const float*)d_in[16];
    const float* tc_wskip = (const float*)d_in[17];
    const float* tc_bskip = (const float*)d_in[18];
    const float* tc_lng   = (const float*)d_in[19];
    const float* tc_lnb   = (const float*)d_in[20];
    const float* cross_w  = (const float*)d_in[21];
    const float* cross_b  = (const float*)d_in[22];
    const float* agg_w    = (const float*)d_in[23];
    const float* agg_b    = (const float*)d_in[24];
    const float* nh_g     = (const float*)d_in[25];
    const float* nh_b     = (const float*)d_in[26];
    const float* nl_g     = (const float*)d_in[27];
    const float* nl_b     = (const float*)d_in[28];

    float* out = (float*)d_out;
    float* out_high = out;
    float* out_low  = out + N_CELLS * D;

    const size_t LOW_N = (size_t)N_CELLS * N_GENES * D;   // 16777216

    unsigned short* q_b = (unsigned short*)d_ws;
    unsigned short* k_b = q_b + LOW_N;
    unsigned short* v_b = k_b + LOW_N;
    unsigned short* vt_b = v_b + LOW_N;
    float* ws_high_out  = (float*)(vt_b + LOW_N);
    float* ws_gene_agg  = ws_high_out + N_CELLS * D;
    float* ws_low_cross = ws_gene_agg + N_CELLS * D;
    unsigned short* wt4 = (unsigned short*)(ws_low_cross + N_CELLS * D);
    unsigned* cnt4 = (unsigned*)(wt4 + 4 * 128 * 128);
    int* sp_off  = (int*)(cnt4 + 8192);
    int* sp_src  = sp_off + 516;

    // prep: spatial CSR, GRN counts, weight transpose
    sp_csr_kernel<<<1, 512, 0, stream>>>(sp, sp_off, sp_src);
    hipMemsetAsync(cnt4, 0, 8192 * sizeof(unsigned), stream);
    cnt_build_kernel<<<E_GRN / 256, 256, 0, stream>>>(grn, cnt4);
    wt_kernel<<<4, 256, 0, stream>>>(tc_wq, tc_wk, tc_wv, tc_wskip, wt4);

    // high level GIN
    gin_mlp_kernel<<<N_CELLS, 256, 0, stream>>>(high_emb, sp_off, sp_src, gin_eps,
        gin_w1, gin_b1, gin_w2, gin_b2, gin_lng, gin_lnb, ws_high_out);

    // projections (MFMA) -> q,k,v bf16 + skip f32 (in out_low)
    proj4_kernel<<<N_CELLS * N_GENES / 128, 256, 0, stream>>>(
        low_emb, wt4, tc_bq, tc_bk, tc_bv, tc_bskip, q_b, k_b, v_b, out_low);

    // per-cell V transpose for PV A-fragments
    vt_kernel<<<N_CELLS, 256, 0, stream>>>(v_b, vt_b);

    // dense masked attention + skip + LN (136KB dynamic LDS)
    attn_dense_kernel<<<N_CELLS, 256, 139264, stream>>>(
        q_b, k_b, vt_b, cnt4, tc_lng, tc_lnb, out_low);

    // gene aggregation
    gene_agg_kernel<<<N_CELLS, 128, 0, stream>>>(out_low, agg_w, agg_b, ws_gene_agg);

    // cross gating + high LN
    cross_kernel<<<N_CELLS, 128, 0, stream>>>(high_emb, ws_high_out, ws_gene_agg,
        cross_w, cross_b, nh_g, nh_b, out_high, ws_low_cross);

    // final low LN
    low_final_kernel<<<N_CELLS * N_GENES, 128, 0, stream>>>(
        low_emb, ws_low_cross, nl_g, nl_b, out_low);
}